// Round 19
// baseline (76.764 us; speedup 1.0000x reference)
//
#include <hip/hip_runtime.h>

// CTC batch cost (Keras: blank=C-1, full lengths).
// Structure (proven absmax 0.0): fwd/bwd split, 128 blocks.
//   block 2b+0: forward alpha t=0..511; block 2b+1: backward beta t=1023..512;
//   P(y) = sum_s alpha_511[s]*beta_511[s] via ctc_combine.
// R19 change: consumer was the pacer (~174 cyc/step); its random-label LDS
//   gathers (bank = label%32, ~6-way collisions) and EPS adds move to the
//   producer wave (which had ~2000 cyc slack/chunk). 3-stage pipeline:
//     VMEM stage rows chunk c+2 -> rowbuf[(c+2)&1]        (global_load_lds)
//     producer ds-gathers chunk c+1 -> cmp[(c+1)&1]       (conflicts hidden)
//     consumer eats cmp[c&1]: 1 conflict-free ds_read_b64 + 1 broadcast b32.
//   cmp is written in CONSUMPTION order (bwd pre-reversed by producer).
//   Ordering: counted vmcnt(32) (VMEM->gather), lgkmcnt(0)+s_barrier
//   (gather->consume). Rescale machinery identical to R18.

constexpr int   B_DIM = 64;
constexpr int   T_LEN = 1024;
constexpr int   C_DIM = 512;
constexpr int   L_LEN = 128;
constexpr int   BLANK = C_DIM - 1;
constexpr int   HALF  = T_LEN / 2;     // 512 steps per direction
constexpr int   TC    = 16;            // timesteps per chunk
constexpr int   NCH   = HALF / TC;     // 32 chunks
constexpr float EPSF  = 1e-7f;
constexpr float LN2F  = 0.69314718055994530942f;

// DPP lane shifts (bound_ctrl=0-fill). 0x138: lane l <- l-1 (verified R2-R18).
__device__ __forceinline__ float wshr1_f(float x) {
    return __int_as_float(__builtin_amdgcn_update_dpp(
        0, __float_as_int(x), 0x138, 0xf, 0xf, true));
}
__device__ __forceinline__ int wshr1_i(int x) {
    return __builtin_amdgcn_update_dpp(0, x, 0x138, 0xf, 0xf, true);
}
// 0x130: lane l <- l+1 (wave_shl:1), lane 63 gets 0.
__device__ __forceinline__ float wshl1_f(float x) {
    return __int_as_float(__builtin_amdgcn_update_dpp(
        0, __float_as_int(x), 0x130, 0xf, 0xf, true));
}
__device__ __forceinline__ int wshl1_i(int x) {
    return __builtin_amdgcn_update_dpp(0, x, 0x130, 0xf, 0xf, true);
}

__global__ __launch_bounds__(128, 1)
void ctc_fb(const int* __restrict__ yt, const float* __restrict__ yh,
            float* __restrict__ st)
{
    __shared__ float  rowbuf[2][TC][C_DIM];   // 64 KB raw rows
    __shared__ float2 cmp[2][TC][64];         // 16 KB compact (P1,P3)+EPS
    __shared__ float  blk[2][TC];             // blank+EPS per step

    const int bid  = blockIdx.x;
    const int b    = bid >> 1;
    const int dir  = bid & 1;                 // 0 = forward, 1 = backward
    const int tid  = threadIdx.x;
    const int lane = tid & 63;
    const int wid  = tid >> 6;                // 0 consumer, 1 producer

    const int* __restrict__ lb = yt + b * L_LEN;
    const float* __restrict__ yhb = yh + (size_t)b * T_LEN * C_DIM;

    const int l0 = lb[2 * lane];              // column for state 4l+1
    const int l1 = lb[2 * lane + 1];          // column for state 4l+3

    if (wid == 1) {
        // ---- producer: stream rows + pre-gather compact --------------------
        auto stageRows = [&](int ch) {        // TC rows x 2 dwordx4 = 32 loads
            float* d = &rowbuf[ch & 1][0][0];
            const int row0 = dir == 0 ? ch * TC : T_LEN - TC * (ch + 1);
            const float* g = yhb + (size_t)row0 * C_DIM + lane * 4;
#pragma unroll
            for (int i = 0; i < TC; ++i) {
#pragma unroll
                for (int h = 0; h < 2; ++h) {
                    __builtin_amdgcn_global_load_lds(
                        (const __attribute__((address_space(1))) void*)
                            (g + i * C_DIM + h * 256),
                        (__attribute__((address_space(3))) void*)
                            (d + i * C_DIM + h * 256),
                        16, 0, 0);
                }
            }
        };
        auto gatherCmp = [&](int ch) {        // rowbuf[ch&1] -> cmp[ch&1]
            const float* r = &rowbuf[ch & 1][0][0];
#pragma unroll
            for (int i = 0; i < TC; ++i) {
                const int rr = dir == 0 ? i : TC - 1 - i;   // consumption order
                const float v1 = r[rr * C_DIM + l0];
                const float v3 = r[rr * C_DIM + l1];
                const float vb = r[rr * C_DIM + BLANK];
                cmp[ch & 1][i][lane] = make_float2(v1 + EPSF, v3 + EPSF);
                if (lane == 0) blk[ch & 1][i] = vb + EPSF;
            }
        };

        asm volatile("s_waitcnt vmcnt(0)" ::: "memory");   // clean count baseline
        stageRows(0);
        stageRows(1);                                      // 64 outstanding
        asm volatile("s_waitcnt vmcnt(32)" ::: "memory");  // rows 0 landed
        gatherCmp(0);
        asm volatile("s_waitcnt lgkmcnt(0)" ::: "memory"); // cmp0 committed
        __builtin_amdgcn_sched_barrier(0);
        __builtin_amdgcn_s_barrier();
#pragma unroll 1
        for (int c = 0; c < NCH; ++c) {
            if (c + 2 < NCH) {
                stageRows(c + 2);                          // -> rowbuf[c&1] (free)
                asm volatile("s_waitcnt vmcnt(32)" ::: "memory"); // rows c+1 landed
            } else {
                asm volatile("s_waitcnt vmcnt(0)" ::: "memory");  // tail drain
            }
            if (c + 1 < NCH) gatherCmp(c + 1);
            asm volatile("s_waitcnt lgkmcnt(0)" ::: "memory");    // writes committed
            __builtin_amdgcn_sched_barrier(0);
            __builtin_amdgcn_s_barrier();
        }
        return;
    }

    // -------- consumer: conflict-free compact reads ------------------------
    float* me = st + ((size_t)(dir * B_DIM + b) * 64 + lane) * 6;

    if (dir == 0) {
        // ================= forward: alpha_0 .. alpha_511 ===================
        const int lp = lane ? lb[2 * lane - 1] : 0;
        const float sk1 = (lane > 0 && l0 != lp && l0 != BLANK) ? 1.0f : 0.0f;
        const float sk3 = (l1 != l0 && l1 != BLANK) ? 1.0f : 0.0f;

        float a0 = (lane == 0) ? 1.0f : 0.0f;   // "t=-1" init trick
        float a1 = 0.0f, a2 = 0.0f, a3 = 0.0f, a4 = 0.0f;
        int   E  = 0;
        float sSeed = (lane == 0) ? 0.0f : 1.0f;

        __builtin_amdgcn_s_barrier();

        float2 r13[8]; float rbk[8];
#pragma unroll 1
        for (int c = 0; c < NCH; ++c) {
            __builtin_amdgcn_sched_barrier(0);
            const float2* cp = &cmp[c & 1][0][0];
            const float*  bp = &blk[c & 1][0];
#pragma unroll
            for (int i = 0; i < 8; ++i) { r13[i] = cp[i * 64 + lane]; rbk[i] = bp[i]; }
#pragma unroll
            for (int tq = 0; tq < 2; ++tq) {
#pragma unroll
                for (int i = 0; i < 8; ++i) {
                    const float P1 = r13[i].x;
                    const float P3 = r13[i].y;
                    const float Pb = rbk[i];
                    if (tq == 0) { r13[i] = cp[(i + 8) * 64 + lane]; rbk[i] = bp[i + 8]; }

                    const float pa3 = wshr1_f(a3) * sSeed;
                    const float n0 = Pb * (a0 + pa3);
                    const float n1 = P1 * (a1 + a0 + sk1 * pa3);
                    const float n2 = Pb * (a2 + a1);
                    const float n3 = P3 * (a3 + a2 + sk3 * a1);
                    const float n4 = Pb * (a4 + a3);
                    a0 = n0; a1 = n1; a2 = n2; a3 = n3; a4 = n4;

                    if ((i & 3) == 3) {
                        const float m = fmaxf(fmaxf(fmaxf(a0, a1), fmaxf(a2, a3)), a4);
                        const bool has = m > 0.0f;
                        int eb = (int)((__float_as_uint(m) >> 23) & 0xFFu);
                        eb = eb < 1 ? 1 : eb;
                        if (has) {
                            const float scl = __uint_as_float((unsigned)(254 - eb) << 23);
                            a0 *= scl; a1 *= scl; a2 *= scl; a3 *= scl; a4 *= scl;
                            E += eb - 127;
                        }
                        int pE = wshr1_i(E);
                        if (!has && lane > 0) E = pE;
                        pE = wshr1_i(E);
                        const int d = pE - E;
                        sSeed = (lane == 0 || d < -126)
                              ? 0.0f
                              : __uint_as_float((unsigned)(127 + (d > 126 ? 126 : d)) << 23);
                    }
                }
            }
            __builtin_amdgcn_sched_barrier(0);
            __builtin_amdgcn_s_barrier();
        }
        me[0] = a0; me[1] = a1; me[2] = a2; me[3] = a3; me[4] = a4;
        me[5] = __int_as_float(E);
    } else {
        // ================= backward: gamma_1023 -> gamma_511 ===============
        const float skb1 = (l1 != l0 && l1 != BLANK) ? 1.0f : 0.0f;   // 4l+1 -> 4l+3
        const int ln = (lane < 63) ? lb[2 * lane + 2] : 0;            // label(4l+5)
        const float skb3 = (lane < 63 && ln != l1 && ln != BLANK) ? 1.0f : 0.0f;

        float c0 = 0.0f, c1 = 0.0f, c2 = 0.0f;
        float c3 = (lane == 63) ? 1.0f : 0.0f;   // gamma_1023[255]=1
        float c4 = (lane == 63) ? 1.0f : 0.0f;   // gamma_1023[256]=1
        int   E  = 0;
        float sSeed = (lane == 63) ? 0.0f : 1.0f;

        __builtin_amdgcn_s_barrier();

        float2 r13[8]; float rbk[8];
#pragma unroll 1
        for (int c = 0; c < NCH; ++c) {
            __builtin_amdgcn_sched_barrier(0);
            const float2* cp = &cmp[c & 1][0][0];   // already in t-descending order
            const float*  bp = &blk[c & 1][0];
#pragma unroll
            for (int i = 0; i < 8; ++i) { r13[i] = cp[i * 64 + lane]; rbk[i] = bp[i]; }
#pragma unroll
            for (int tq = 0; tq < 2; ++tq) {
#pragma unroll
                for (int i = 0; i < 8; ++i) {
                    const float P1 = r13[i].x;
                    const float P3 = r13[i].y;
                    const float Pb = rbk[i];
                    if (tq == 0) { r13[i] = cp[(i + 8) * 64 + lane]; rbk[i] = bp[i + 8]; }

                    const float bn0 = c0 * Pb;
                    const float bn1 = c1 * P1;
                    const float bn2 = c2 * Pb;
                    const float bn3 = c3 * P3;
                    const float bn4 = c4 * Pb;            // == neighbor's bn0
                    const float x1  = wshl1_f(bn1) * sSeed;
                    c0 = bn0 + bn1;
                    c1 = bn1 + bn2 + skb1 * bn3;
                    c2 = bn2 + bn3;
                    c3 = bn3 + bn4 + skb3 * x1;
                    c4 = bn4 + x1;

                    if ((i & 3) == 3) {
                        const float m = fmaxf(fmaxf(fmaxf(c0, c1), fmaxf(c2, c3)), c4);
                        const bool has = m > 0.0f;
                        int eb = (int)((__float_as_uint(m) >> 23) & 0xFFu);
                        eb = eb < 1 ? 1 : eb;
                        if (has) {
                            const float scl = __uint_as_float((unsigned)(254 - eb) << 23);
                            c0 *= scl; c1 *= scl; c2 *= scl; c3 *= scl; c4 *= scl;
                            E += eb - 127;
                        }
                        int pE = wshl1_i(E);
                        if (!has && lane < 63) E = pE;
                        pE = wshl1_i(E);
                        const int d = pE - E;
                        sSeed = (lane == 63 || d < -126)
                              ? 0.0f
                              : __uint_as_float((unsigned)(127 + (d > 126 ? 126 : d)) << 23);
                    }
                }
            }
            __builtin_amdgcn_sched_barrier(0);
            __builtin_amdgcn_s_barrier();
        }
        me[0] = c0; me[1] = c1; me[2] = c2; me[3] = c3; me[4] = c4;
        me[5] = __int_as_float(E);
    }
}

__global__ __launch_bounds__(64)
void ctc_combine(const float* __restrict__ st, float* __restrict__ out)
{
    const int b    = blockIdx.x;
    const int lane = threadIdx.x;
    const float* f = st + ((size_t)b * 64 + lane) * 6;
    const float* g = st + ((size_t)(B_DIM + b) * 64 + lane) * 6;

    float v = f[0] * g[0] + f[1] * g[1] + f[2] * g[2] + f[3] * g[3];
    if (lane == 63) v += f[4] * g[4];        // state 256
    const int e = __float_as_int(f[5]) + __float_as_int(g[5]);
    float L = (v > 0.0f) ? (log2f(v) + (float)e) : -1e30f;

    float M = L;
#pragma unroll
    for (int d = 1; d < 64; d <<= 1) M = fmaxf(M, __shfl_xor(M, d));
    float s = (L > -1e29f) ? exp2f(L - M) : 0.0f;
#pragma unroll
    for (int d = 1; d < 64; d <<= 1) s += __shfl_xor(s, d);

    if (lane == 0) out[b] = -((M + log2f(s)) * LN2F);
}

extern "C" void kernel_launch(void* const* d_in, const int* in_sizes, int n_in,
                              void* d_out, int out_size, void* d_ws, size_t ws_size,
                              hipStream_t stream)
{
    const int*   yt  = (const int*)d_in[0];
    const float* yh  = (const float*)d_in[1];
    float*       out = (float*)d_out;
    float*       st  = (float*)d_ws;       // 2*64*64*6 floats = 192 KB << ws
    ctc_fb<<<dim3(2 * B_DIM), dim3(128), 0, stream>>>(yt, yh, st);
    ctc_combine<<<dim3(B_DIM), dim3(64), 0, stream>>>(st, out);
}

// Round 20
// 40.479 us; speedup vs baseline: 1.8964x; 1.8964x over previous
//
#include <hip/hip_runtime.h>

// CTC batch cost (Keras: blank=C-1, full lengths).
// Structure (all pieces individually proven):
//   fwd/bwd split (R17, 2x): 128 blocks; block 2b+0 = forward alpha t=0..511,
//   block 2b+1 = backward beta t=1023..512; P(y)=sum_s alpha*beta (combine).
//   Producer (R16 pattern): wave1 streams whole 2KB rows into LDS
//   (global_load_lds dwordx4), TC=32, NBUF=2 (128KB), drain-to-0 + raw
//   s_barrier (counted vmcnt measured no better -- R18; drain hides under
//   the consumer's ~4600cyc chunk).
//   Consumer (R17): 8-deep LDS ring (3 gathers/step overlapped with DP),
//   DPP wave_shr/shl cross-lane, per-lane pow2 rescale every 4 steps.
// R19 lesson (reverted): moving gathers to the producer exposed their
//   latency serially (41->77us); conflicts were never the cost.
// R16 vs R17 fit: barrier overhead ~480cyc/chunk -> TC=32 beats TC=16.

constexpr int   B_DIM = 64;
constexpr int   T_LEN = 1024;
constexpr int   C_DIM = 512;
constexpr int   L_LEN = 128;
constexpr int   BLANK = C_DIM - 1;
constexpr int   HALF  = T_LEN / 2;     // 512 steps per direction
constexpr int   TC    = 32;            // timesteps per chunk
constexpr int   NCH   = HALF / TC;     // 16 chunks
constexpr float EPSF  = 1e-7f;
constexpr float LN2F  = 0.69314718055994530942f;

// DPP lane shifts (bound_ctrl=0-fill). 0x138: lane l <- l-1 (verified R2-R18).
__device__ __forceinline__ float wshr1_f(float x) {
    return __int_as_float(__builtin_amdgcn_update_dpp(
        0, __float_as_int(x), 0x138, 0xf, 0xf, true));
}
__device__ __forceinline__ int wshr1_i(int x) {
    return __builtin_amdgcn_update_dpp(0, x, 0x138, 0xf, 0xf, true);
}
// 0x130: lane l <- l+1 (wave_shl:1), lane 63 gets 0. (verified R17)
__device__ __forceinline__ float wshl1_f(float x) {
    return __int_as_float(__builtin_amdgcn_update_dpp(
        0, __float_as_int(x), 0x130, 0xf, 0xf, true));
}
__device__ __forceinline__ int wshl1_i(int x) {
    return __builtin_amdgcn_update_dpp(0, x, 0x130, 0xf, 0xf, true);
}

__global__ __launch_bounds__(128, 1)
void ctc_fb(const int* __restrict__ yt, const float* __restrict__ yh,
            float* __restrict__ st)
{
    __shared__ float sbuf[2][TC][C_DIM];      // 128 KB

    const int bid  = blockIdx.x;
    const int b    = bid >> 1;
    const int dir  = bid & 1;                 // 0 = forward, 1 = backward
    const int tid  = threadIdx.x;
    const int lane = tid & 63;
    const int wid  = tid >> 6;                // 0 consumer, 1 producer

    const int* __restrict__ lb = yt + b * L_LEN;
    const float* __restrict__ yhb = yh + (size_t)b * T_LEN * C_DIM;

    if (wid == 1) {
        // ---- producer: stream whole rows coalesced (R16 pattern) ----------
        auto stage = [&](int ch) {            // TC rows x 2 dwordx4 = 64 loads
            float* d = &sbuf[ch & 1][0][0];
            const int row0 = dir == 0 ? ch * TC : T_LEN - TC * (ch + 1);
            const float* g = yhb + (size_t)row0 * C_DIM + lane * 4;
#pragma unroll
            for (int i = 0; i < TC; ++i) {
#pragma unroll
                for (int h = 0; h < 2; ++h) {
                    __builtin_amdgcn_global_load_lds(
                        (const __attribute__((address_space(1))) void*)
                            (g + i * C_DIM + h * 256),
                        (__attribute__((address_space(3))) void*)
                            (d + i * C_DIM + h * 256),
                        16, 0, 0);
                }
            }
        };
        stage(0);
        asm volatile("s_waitcnt vmcnt(0)" ::: "memory");
        __builtin_amdgcn_sched_barrier(0);
        __builtin_amdgcn_s_barrier();                      // raw: no auto-drain
#pragma unroll 1
        for (int c = 0; c < NCH; ++c) {
            if (c + 1 < NCH) stage(c + 1);                 // lands under consumer chunk
            asm volatile("s_waitcnt vmcnt(0)" ::: "memory");
            __builtin_amdgcn_sched_barrier(0);
            __builtin_amdgcn_s_barrier();
        }
        return;
    }

    // -------- consumer -----------------------------------------------------
    const int l0 = lb[2 * lane];
    const int l1 = lb[2 * lane + 1];
    float* me = st + ((size_t)(dir * B_DIM + b) * 64 + lane) * 6;

    if (dir == 0) {
        // ================= forward: alpha_0 .. alpha_511 ===================
        const int lp = lane ? lb[2 * lane - 1] : 0;
        const float sk1 = (lane > 0 && l0 != lp && l0 != BLANK) ? 1.0f : 0.0f;
        const float sk3 = (l1 != l0 && l1 != BLANK) ? 1.0f : 0.0f;

        float a0 = (lane == 0) ? 1.0f : 0.0f;   // "t=-1" init trick
        float a1 = 0.0f, a2 = 0.0f, a3 = 0.0f, a4 = 0.0f;
        int   E  = 0;
        float sSeed = (lane == 0) ? 0.0f : 1.0f;

        __builtin_amdgcn_s_barrier();

        float r1[8], r3[8], rb[8];
#pragma unroll 1
        for (int c = 0; c < NCH; ++c) {
            __builtin_amdgcn_sched_barrier(0);
            const float* sb = &sbuf[c & 1][0][0];
#pragma unroll
            for (int i = 0; i < 8; ++i) {
                r1[i] = sb[i * C_DIM + l0];
                r3[i] = sb[i * C_DIM + l1];
                rb[i] = sb[i * C_DIM + BLANK];
            }
#pragma unroll
            for (int tq = 0; tq < TC / 8; ++tq) {
#pragma unroll
                for (int i = 0; i < 8; ++i) {
                    const float P1 = r1[i] + EPSF;
                    const float P3 = r3[i] + EPSF;
                    const float Pb = rb[i] + EPSF;
                    if (tq < TC / 8 - 1) {
                        const int tn = tq * 8 + i + 8;
                        r1[i] = sb[tn * C_DIM + l0];
                        r3[i] = sb[tn * C_DIM + l1];
                        rb[i] = sb[tn * C_DIM + BLANK];
                    }
                    const float pa3 = wshr1_f(a3) * sSeed;
                    const float n0 = Pb * (a0 + pa3);
                    const float n1 = P1 * (a1 + a0 + sk1 * pa3);
                    const float n2 = Pb * (a2 + a1);
                    const float n3 = P3 * (a3 + a2 + sk3 * a1);
                    const float n4 = Pb * (a4 + a3);
                    a0 = n0; a1 = n1; a2 = n2; a3 = n3; a4 = n4;

                    if ((i & 3) == 3) {
                        const float m = fmaxf(fmaxf(fmaxf(a0, a1), fmaxf(a2, a3)), a4);
                        const bool has = m > 0.0f;
                        int eb = (int)((__float_as_uint(m) >> 23) & 0xFFu);
                        eb = eb < 1 ? 1 : eb;
                        if (has) {
                            const float scl = __uint_as_float((unsigned)(254 - eb) << 23);
                            a0 *= scl; a1 *= scl; a2 *= scl; a3 *= scl; a4 *= scl;
                            E += eb - 127;
                        }
                        int pE = wshr1_i(E);
                        if (!has && lane > 0) E = pE;
                        pE = wshr1_i(E);
                        const int d = pE - E;
                        sSeed = (lane == 0 || d < -126)
                              ? 0.0f
                              : __uint_as_float((unsigned)(127 + (d > 126 ? 126 : d)) << 23);
                    }
                }
            }
            __builtin_amdgcn_sched_barrier(0);
            __builtin_amdgcn_s_barrier();
        }
        me[0] = a0; me[1] = a1; me[2] = a2; me[3] = a3; me[4] = a4;
        me[5] = __int_as_float(E);
    } else {
        // ================= backward: gamma_1023 -> gamma_511 ===============
        const float skb1 = (l1 != l0 && l1 != BLANK) ? 1.0f : 0.0f;   // 4l+1 -> 4l+3
        const int ln = (lane < 63) ? lb[2 * lane + 2] : 0;            // label(4l+5)
        const float skb3 = (lane < 63 && ln != l1 && ln != BLANK) ? 1.0f : 0.0f;

        float c0 = 0.0f, c1 = 0.0f, c2 = 0.0f;
        float c3 = (lane == 63) ? 1.0f : 0.0f;   // gamma_1023[255]=1
        float c4 = (lane == 63) ? 1.0f : 0.0f;   // gamma_1023[256]=1
        int   E  = 0;
        float sSeed = (lane == 63) ? 0.0f : 1.0f;

        __builtin_amdgcn_s_barrier();

        float r1[8], r3[8], rb[8];
#pragma unroll 1
        for (int c = 0; c < NCH; ++c) {
            __builtin_amdgcn_sched_barrier(0);
            const float* sb = &sbuf[c & 1][0][0];
            // step j consumes LDS row (TC-1-j): t descending within chunk
#pragma unroll
            for (int i = 0; i < 8; ++i) {
                const int rr = TC - 1 - i;
                r1[i] = sb[rr * C_DIM + l0];
                r3[i] = sb[rr * C_DIM + l1];
                rb[i] = sb[rr * C_DIM + BLANK];
            }
#pragma unroll
            for (int tq = 0; tq < TC / 8; ++tq) {
#pragma unroll
                for (int i = 0; i < 8; ++i) {
                    const float P1 = r1[i] + EPSF;
                    const float P3 = r3[i] + EPSF;
                    const float Pb = rb[i] + EPSF;
                    if (tq < TC / 8 - 1) {
                        const int rr = TC - 1 - (tq * 8 + i + 8);
                        r1[i] = sb[rr * C_DIM + l0];
                        r3[i] = sb[rr * C_DIM + l1];
                        rb[i] = sb[rr * C_DIM + BLANK];
                    }
                    const float bn0 = c0 * Pb;
                    const float bn1 = c1 * P1;
                    const float bn2 = c2 * Pb;
                    const float bn3 = c3 * P3;
                    const float bn4 = c4 * Pb;            // == neighbor's bn0
                    const float x1  = wshl1_f(bn1) * sSeed;
                    c0 = bn0 + bn1;
                    c1 = bn1 + bn2 + skb1 * bn3;
                    c2 = bn2 + bn3;
                    c3 = bn3 + bn4 + skb3 * x1;
                    c4 = bn4 + x1;

                    if ((i & 3) == 3) {
                        const float m = fmaxf(fmaxf(fmaxf(c0, c1), fmaxf(c2, c3)), c4);
                        const bool has = m > 0.0f;
                        int eb = (int)((__float_as_uint(m) >> 23) & 0xFFu);
                        eb = eb < 1 ? 1 : eb;
                        if (has) {
                            const float scl = __uint_as_float((unsigned)(254 - eb) << 23);
                            c0 *= scl; c1 *= scl; c2 *= scl; c3 *= scl; c4 *= scl;
                            E += eb - 127;
                        }
                        int pE = wshl1_i(E);
                        if (!has && lane < 63) E = pE;
                        pE = wshl1_i(E);
                        const int d = pE - E;
                        sSeed = (lane == 63 || d < -126)
                              ? 0.0f
                              : __uint_as_float((unsigned)(127 + (d > 126 ? 126 : d)) << 23);
                    }
                }
            }
            __builtin_amdgcn_sched_barrier(0);
            __builtin_amdgcn_s_barrier();
        }
        me[0] = c0; me[1] = c1; me[2] = c2; me[3] = c3; me[4] = c4;
        me[5] = __int_as_float(E);
    }
}

__global__ __launch_bounds__(64)
void ctc_combine(const float* __restrict__ st, float* __restrict__ out)
{
    const int b    = blockIdx.x;
    const int lane = threadIdx.x;
    const float* f = st + ((size_t)b * 64 + lane) * 6;
    const float* g = st + ((size_t)(B_DIM + b) * 64 + lane) * 6;

    float v = f[0] * g[0] + f[1] * g[1] + f[2] * g[2] + f[3] * g[3];
    if (lane == 63) v += f[4] * g[4];        // state 256
    const int e = __float_as_int(f[5]) + __float_as_int(g[5]);
    float L = (v > 0.0f) ? (log2f(v) + (float)e) : -1e30f;

    float M = L;
#pragma unroll
    for (int d = 1; d < 64; d <<= 1) M = fmaxf(M, __shfl_xor(M, d));
    float s = (L > -1e29f) ? exp2f(L - M) : 0.0f;
#pragma unroll
    for (int d = 1; d < 64; d <<= 1) s += __shfl_xor(s, d);

    if (lane == 0) out[b] = -((M + log2f(s)) * LN2F);
}

extern "C" void kernel_launch(void* const* d_in, const int* in_sizes, int n_in,
                              void* d_out, int out_size, void* d_ws, size_t ws_size,
                              hipStream_t stream)
{
    const int*   yt  = (const int*)d_in[0];
    const float* yh  = (const float*)d_in[1];
    float*       out = (float*)d_out;
    float*       st  = (float*)d_ws;       // 2*64*64*6 floats = 192 KB << ws
    ctc_fb<<<dim3(2 * B_DIM), dim3(128), 0, stream>>>(yt, yh, st);
    ctc_combine<<<dim3(B_DIM), dim3(64), 0, stream>>>(st, out);
}